// Round 5
// baseline (349.139 us; speedup 1.0000x reference)
//
#include <hip/hip_runtime.h>

// ---------------------------------------------------------------------------
// Fused MHA: B=2, T=2048, M=2048, H=16, D=128, causal, qk-centered-RMS-norm,
// half-split rotary, QK_SCALE = 1/D.
// Pipeline: cast/transposes -> QKV GEMM (256^2 8-wave, 4-quadrant phase
// schedule) -> norm+rope -> flash attn (async-stage + defer-max) -> out GEMM.
// ---------------------------------------------------------------------------

#define NB 2
#define NT 2048
#define NM 2048
#define NH 16
#define ND 128

typedef __attribute__((ext_vector_type(4))) float f32x4;
typedef __attribute__((ext_vector_type(8))) short bf16x8;
typedef __attribute__((ext_vector_type(4))) short bf16x4;

#define AS1 __attribute__((address_space(1)))
#define AS3 __attribute__((address_space(3)))

__device__ __forceinline__ unsigned short f2bf(float f){
  unsigned int u = __float_as_uint(f);
  u = (u + 0x7fffu + ((u >> 16) & 1u)) >> 16;   // RNE
  return (unsigned short)u;
}
__device__ __forceinline__ float bf2f(short s){
  return __uint_as_float(((unsigned int)(unsigned short)s) << 16);
}
__device__ __forceinline__ float wredsum(float v){
  #pragma unroll
  for (int m = 1; m < 64; m <<= 1) v += __shfl_xor(v, m);
  return v;
}
__device__ __forceinline__ void gload_lds16(const void* g, void* l){
  __builtin_amdgcn_global_load_lds((const AS1 void*)g, (AS3 void*)l, 16, 0, 0);
}

// ---------------- rope cos/sin table: [T][64] each --------------------------
__global__ __launch_bounds__(64) void rope_table_k(float* ctab, float* stab){
  int t = blockIdx.x, i = threadIdx.x;
  float freq = __expf(-(float)i * (9.210340371976184f / 64.0f)); // ln(10000)
  float ang = (float)t * freq;
  ctab[t * 64 + i] = cosf(ang);
  stab[t * 64 + i] = sinf(ang);
}

// ---------------- cast x fp32 -> bf16 --------------------------------------
__global__ __launch_bounds__(256) void cast_x_k(const float* __restrict__ x,
                                                short* __restrict__ xb){
  size_t gid = (size_t)blockIdx.x * 256 + threadIdx.x;
  float4 v = *(const float4*)(x + gid * 4);
  bf16x4 o;
  o[0] = (short)f2bf(v.x); o[1] = (short)f2bf(v.y);
  o[2] = (short)f2bf(v.z); o[3] = (short)f2bf(v.w);
  *(bf16x4*)(xb + gid * 4) = o;
}

// ------------- transpose weights fp32 [K][N] -> bf16 [N][K] ----------------
__global__ __launch_bounds__(256) void transpose_w_k(const float* __restrict__ wq,
                                                     const float* __restrict__ wk,
                                                     const float* __restrict__ wv,
                                                     const float* __restrict__ wo,
                                                     short* __restrict__ wT){
  __shared__ float tl[32][33];
  int z = blockIdx.z;
  const float* src = (z == 0) ? wq : (z == 1) ? wk : (z == 2) ? wv : wo;
  short* dst = wT + (size_t)z * 2048 * 2048;
  int n0 = blockIdx.x * 32, k0 = blockIdx.y * 32;
  int cx = threadIdx.x & 31, ry = threadIdx.x >> 5; // 0..7
  #pragma unroll
  for (int p = 0; p < 4; ++p)
    tl[ry + 8 * p][cx] = src[(size_t)(k0 + ry + 8 * p) * 2048 + n0 + cx];
  __syncthreads();
  #pragma unroll
  for (int p = 0; p < 4; ++p)
    dst[(size_t)(n0 + ry + 8 * p) * 2048 + k0 + cx] =
        (short)f2bf(tl[cx][ry + 8 * p]);
}

// ---------------------------------------------------------------------------
// QKV GEMM: C[4096 x 6144] = A[4096 x 2048] * B^T[6144 x 2048] (bf16)
// 256x256 tile, BK=64, 8 waves (2M x 4N), 512 threads, 128 KiB dynamic LDS.
// 4-quadrant phase schedule per K-tile:
//   phase q: {12 ds_reads, stage 1/4 of kt+1 (2 gload_lds), mid-barrier,
//             setprio(1), 16 MFMA, setprio(0), end-barrier}
// Boundary: vmcnt(0) (loads >=1 phase old) + barrier publishes buffer.
// ---------------------------------------------------------------------------
#define NKT 32   // 2048 / 64
__global__ __launch_bounds__(512, 2) void gemm256_k(const short* __restrict__ A,
                                                    const short* __restrict__ Bt,
                                                    short* __restrict__ Cq){
  extern __shared__ char lds[];
  const int tid = threadIdx.x;
  const int wid = tid >> 6, lane = tid & 63;
  const int lrow = lane & 15, g8 = lane >> 4;
  const int wm = wid >> 2, wn = wid & 3;
  const int Kdim = 2048;

  // XCD-aware bijective swizzle over 384 blocks (384 % 8 == 0)
  int bid = blockIdx.x;
  int s = (bid & 7) * 48 + (bid >> 3);
  const int bx = s & 15;        // 16 m-tiles
  const int by = s >> 4;        // 24 n-tiles
  const int m0 = bx * 256, n0 = by * 256;

  // staging: thread covers row = wid*8 + (lane>>3), pre-swizzled k granule
  const int r8 = lane >> 3;
  const int gcol = ((lane & 7) ^ r8) * 8;           // inverse-swizzled source
  const short* Ab = A  + (size_t)(m0 + wid * 8 + r8) * Kdim + gcol;
  const short* Bb = Bt + (size_t)(n0 + wid * 8 + r8) * Kdim + gcol;

  f32x4 acc[8][4] = {};

  // stage quarter q (64 rows of A and of B) of K-tile kt2 into buffer c2
  auto STAGEQ = [&](int c2, int kt2, int q){
    size_t roff = (size_t)(q * 64) * Kdim + kt2 * 64;
    char* la = lds + c2 * 32768 + q * 8192 + wid * 1024;
    gload_lds16(Ab + roff, la);
    gload_lds16(Bb + roff, la + 65536);
  };
  auto ldA = [&](int c, int mi, int kk) -> bf16x8 {
    int row = mi * 16 + lrow;
    int col = (kk * 64 + g8 * 16) ^ ((lrow & 7) << 4);
    return *(const bf16x8*)(lds + c * 32768 + wm * 16384 + row * 128 + col);
  };
  auto ldB = [&](int c, int ni, int kk) -> bf16x8 {
    int row = (wn & 1) * 64 + ni * 16 + lrow;
    int col = (kk * 64 + g8 * 16) ^ ((lrow & 7) << 4);
    return *(const bf16x8*)(lds + 65536 + c * 32768 + (wn >> 1) * 16384 + row * 128 + col);
  };

  // prologue: stage all of kt=0
  #pragma unroll
  for (int q = 0; q < 4; ++q) STAGEQ(0, 0, q);

  for (int kt = 0; kt < NKT; ++kt){
    const int c = kt & 1;
    asm volatile("s_waitcnt vmcnt(0)" ::: "memory");
    __builtin_amdgcn_s_barrier();     // publish buffer c

    #pragma unroll
    for (int q = 0; q < 4; ++q){
      const int qm = q >> 1, qn = q & 1;
      bf16x8 af[4][2], bfv[2][2];
      #pragma unroll
      for (int i = 0; i < 4; ++i)
        #pragma unroll
        for (int kk = 0; kk < 2; ++kk)
          af[i][kk] = ldA(c, qm * 4 + i, kk);
      #pragma unroll
      for (int j = 0; j < 2; ++j)
        #pragma unroll
        for (int kk = 0; kk < 2; ++kk)
          bfv[j][kk] = ldB(c, qn * 2 + j, kk);
      if (kt + 1 < NKT) STAGEQ(c ^ 1, kt + 1, q);
      __builtin_amdgcn_s_barrier();   // mid-phase: absorb LDS service
      __builtin_amdgcn_s_setprio(1);
      #pragma unroll
      for (int kk = 0; kk < 2; ++kk)
        #pragma unroll
        for (int i = 0; i < 4; ++i)
          #pragma unroll
          for (int j = 0; j < 2; ++j)
            acc[qm * 4 + i][qn * 2 + j] = __builtin_amdgcn_mfma_f32_16x16x32_bf16(
                af[i][kk], bfv[j][kk], acc[qm * 4 + i][qn * 2 + j], 0, 0, 0);
      __builtin_amdgcn_s_setprio(0);
      __builtin_amdgcn_s_barrier();   // end-phase
    }
  }

  // ---- scatter epilogue: bf16 into q|k|v [B,H,T,D] ----
  #pragma unroll
  for (int mi = 0; mi < 8; ++mi){
    int rowb = m0 + wm * 128 + mi * 16 + g8 * 4;
    #pragma unroll
    for (int ni = 0; ni < 4; ++ni){
      int col = n0 + wn * 64 + ni * 16 + lrow;
      int tsel = col >> 11;
      int hd = col & 2047;
      int hh = hd >> 7, d = hd & 127;
      short* dst = Cq + (size_t)tsel * (NB * NH * NT * ND);
      f32x4 a = acc[mi][ni];
      #pragma unroll
      for (int r = 0; r < 4; ++r){
        int bt = rowb + r;
        int b = bt >> 11, t = bt & 2047;
        dst[(((size_t)(b * NH + hh)) * NT + t) * ND + d] = (short)f2bf(a[r]);
      }
    }
  }
}

// ---------------- out-proj GEMM (128^2, double-buffered, 1-barrier) --------
// C[4096 x 2048] = A[4096 x K] * B^T[2048 x K], fp32 row-major out
__global__ __launch_bounds__(256) void gemm_bt_k(const short* __restrict__ A,
                                                 const short* __restrict__ Bt,
                                                 float* __restrict__ Cout,
                                                 int Kdim){
  __shared__ short As[2][128 * 32];
  __shared__ short Bs[2][128 * 32];
  const int tid = threadIdx.x;
  const int wid = tid >> 6, lane = tid & 63;
  const int lrow = lane & 15, g8 = lane >> 4;
  const int wm = wid >> 1, wn = wid & 1;
  const int m0 = blockIdx.x * 128, n0 = blockIdx.y * 128;
  f32x4 acc[4][4] = {};
  const int srow = lane >> 2;
  const int skcol = (lane & 3) * 8;

  auto STAGE = [&](int c, int kt){
    #pragma unroll
    for (int i = 0; i < 2; ++i){
      int inst = wid * 2 + i;
      int r = inst * 16 + srow;
      const short* sa = A  + (size_t)(m0 + r) * Kdim + kt + skcol;
      const short* sb = Bt + (size_t)(n0 + r) * Kdim + kt + skcol;
      gload_lds16(sa, (char*)As[c] + inst * 1024);
      gload_lds16(sb, (char*)Bs[c] + inst * 1024);
    }
  };

  STAGE(0, 0);
  const int nkt = Kdim >> 5;
  for (int it = 0; it < nkt; ++it){
    const int c = it & 1;
    asm volatile("s_waitcnt vmcnt(0)" ::: "memory");
    __builtin_amdgcn_s_barrier();
    if (it + 1 < nkt) STAGE(c ^ 1, (it + 1) << 5);

    bf16x8 af[4], bfv[4];
    #pragma unroll
    for (int mi = 0; mi < 4; ++mi)
      af[mi] = *(const bf16x8*)&As[c][(wm * 64 + mi * 16 + lrow) * 32 + g8 * 8];
    #pragma unroll
    for (int ni = 0; ni < 4; ++ni)
      bfv[ni] = *(const bf16x8*)&Bs[c][(wn * 64 + ni * 16 + lrow) * 32 + g8 * 8];
    #pragma unroll
    for (int mi = 0; mi < 4; ++mi)
      #pragma unroll
      for (int ni = 0; ni < 4; ++ni)
        acc[mi][ni] = __builtin_amdgcn_mfma_f32_16x16x32_bf16(
            af[mi], bfv[ni], acc[mi][ni], 0, 0, 0);
  }

  #pragma unroll
  for (int mi = 0; mi < 4; ++mi){
    int rowb = m0 + wm * 64 + mi * 16 + g8 * 4;
    #pragma unroll
    for (int ni = 0; ni < 4; ++ni){
      int col = n0 + wn * 64 + ni * 16 + lrow;
      f32x4 a = acc[mi][ni];
      #pragma unroll
      for (int r = 0; r < 4; ++r)
        Cout[(size_t)(rowb + r) * 2048 + col] = a[r];
    }
  }
}

// -------------- centered RMS norm + rotary (q and k) -----------------------
__global__ __launch_bounds__(256) void norm_rope_k(const short* __restrict__ qkv,
                                                   short* __restrict__ outp,
                                                   const float* __restrict__ gq,
                                                   const float* __restrict__ bq,
                                                   const float* __restrict__ gk,
                                                   const float* __restrict__ bk,
                                                   const float* __restrict__ ctab,
                                                   const float* __restrict__ stab){
  int which = blockIdx.y;
  const short* src = qkv + (size_t)which * (NB * NH * NT * ND);
  short* dst = outp + (size_t)which * (NB * NH * NT * ND);
  const float* g = which ? gk : gq;
  const float* bb = which ? bk : bq;
  int wid = threadIdx.x >> 6, lane = threadIdx.x & 63;
  size_t row = (size_t)blockIdx.x * 4 + wid;  // over B*H*T
  int h = (int)((row >> 11) & 15);
  int t = (int)(row & 2047);
  const short* rp = src + row * ND;
  float v0 = bf2f(rp[lane]), v1 = bf2f(rp[lane + 64]);
  float mean = wredsum(v0 + v1) * (1.0f / 128.0f);
  float c0 = v0 - mean, c1 = v1 - mean;
  float ms = wredsum(c0 * c0 + c1 * c1) * (1.0f / 128.0f);
  float rstd = rsqrtf(ms + 1e-6f);
  float n0 = c0 * rstd * (1.0f + g[h * ND + lane]) + bb[h * ND + lane];
  float n1 = c1 * rstd * (1.0f + g[h * ND + lane + 64]) + bb[h * ND + lane + 64];
  float co = ctab[t * 64 + lane], si = stab[t * 64 + lane];
  short* wp = dst + row * ND;
  wp[lane]      = (short)f2bf(n0 * co - n1 * si);
  wp[lane + 64] = (short)f2bf(n0 * si + n1 * co);
}

// ---------------- flash attention, causal ----------------------------------
// async-STAGE (T14): K/V loads for tile jb+1 issued into regs during tile jb's
// compute; only LDS writes between barriers. defer-max (T13): skip O-rescale
// while __all(mx <= m + 8).
__global__ __launch_bounds__(256) void attn_k(const short* __restrict__ qn,
                                              const short* __restrict__ kn,
                                              const short* __restrict__ vsrc,
                                              short* __restrict__ ob){
  __shared__ short Ks[64 * 128];
  __shared__ short VTs[128 * 64];
  __shared__ short Ps[4][16 * 64];
  const int tid = threadIdx.x;
  const int wid = tid >> 6, lane = tid & 63;
  const int lrow = lane & 15, g8 = lane >> 4;
  const int bh = blockIdx.y;
  const int b = bh >> 4, h = bh & 15;
  const size_t base = (size_t)bh * NT * ND;
  const int sr = tid >> 4;            // staging row 0..15
  const int sc = tid & 15;            // staging col-chunk

  for (int pass = 0; pass < 2; ++pass){
    const int qt = pass ? (31 - (int)blockIdx.x) : (int)blockIdx.x;
    const int t0 = qt * 64;
    const int tq = t0 + wid * 16 + lrow;
    bf16x8 qf[4];
    #pragma unroll
    for (int dc = 0; dc < 4; ++dc)
      qf[dc] = *(const bf16x8*)(qn + base + (size_t)tq * ND + dc * 32 + g8 * 8);
    f32x4 O[8] = {};
    float m = -3e38f, lsum = 0.0f;
    const int ntiles = qt + 1;

    bf16x8 kreg[4], vreg[4];
    #pragma unroll
    for (int p = 0; p < 4; ++p){
      int r = sr + p * 16;
      kreg[p] = *(const bf16x8*)(kn + base + (size_t)r * ND + sc * 8);
      vreg[p] = *(const bf16x8*)(vsrc + base + (size_t)r * ND + sc * 8);
    }

    for (int jb = 0; jb < ntiles; ++jb){
      __syncthreads();
      // ---- write staged K [64][128] swizzled ----
      #pragma unroll
      for (int p = 0; p < 4; ++p){
        int r = sr + p * 16;
        *(bf16x8*)((char*)Ks + r * 256 + ((sc * 16) ^ ((r & 7) << 4))) = kreg[p];
      }
      // ---- scatter staged V^T [128][64] swizzled ----
      #pragma unroll
      for (int p = 0; p < 4; ++p){
        int jr = sr + p * 16;
        int d0 = sc * 8;
        #pragma unroll
        for (int i = 0; i < 8; ++i){
          int d = d0 + i;
          *(short*)((char*)VTs + d * 128 +
                    ((jr * 2) ^ ((((d >> 3) ^ d) & 7) << 4))) = vreg[p][i];
        }
      }
      __syncthreads();
      // ---- preload next tile (overlaps compute below) ----
      if (jb + 1 < ntiles){
        #pragma unroll
        for (int p = 0; p < 4; ++p){
          int r = (jb + 1) * 64 + sr + p * 16;
          kreg[p] = *(const bf16x8*)(kn + base + (size_t)r * ND + sc * 8);
          vreg[p] = *(const bf16x8*)(vsrc + base + (size_t)r * ND + sc * 8);
        }
      }

      if (jb * 64 <= t0 + wid * 16 + 15){
        f32x4 st[4] = {};
        #pragma unroll
        for (int dc = 0; dc < 4; ++dc)
          #pragma unroll
          for (int js = 0; js < 4; ++js){
            int jl = js * 16 + lrow;
            bf16x8 kf = *(const bf16x8*)((char*)Ks + jl * 256 +
                          ((dc * 64 + g8 * 16) ^ ((jl & 7) << 4)));
            st[js] = __builtin_amdgcn_mfma_f32_16x16x32_bf16(kf, qf[dc], st[js], 0, 0, 0);
          }
        float mx = -3e38f;
        #pragma unroll
        for (int js = 0; js < 4; ++js)
          #pragma unroll
          for (int r = 0; r < 4; ++r){
            float s = st[js][r] * (1.0f / 128.0f);
            int j = jb * 64 + js * 16 + g8 * 4 + r;
            if (j > tq) s = -3e38f;
            st[js][r] = s;
            mx = fmaxf(mx, s);
          }
        mx = fmaxf(mx, __shfl_xor(mx, 16));
        mx = fmaxf(mx, __shfl_xor(mx, 32));
        // defer-max: rescale only when the running max actually grows
        if (!__all(mx <= m + 8.0f)){
          float mnew = fmaxf(m, mx);
          float fac = __expf(m - mnew);
          m = mnew;
          lsum *= fac;
          #pragma unroll
          for (int dcb = 0; dcb < 8; ++dcb) O[dcb] *= fac;
        }
        float ps = 0.0f;
        #pragma unroll
        for (int js = 0; js < 4; ++js)
          #pragma unroll
          for (int r = 0; r < 4; ++r){
            float p = __expf(st[js][r] - m);
            ps += p;
            int jl = js * 16 + g8 * 4 + r;
            *(short*)((char*)Ps[wid] + lrow * 128 +
                      ((jl * 2) ^ ((lrow & 7) << 4))) = (short)f2bf(p);
          }
        ps += __shfl_xor(ps, 16);
        ps += __shfl_xor(ps, 32);
        lsum += ps;
        asm volatile("s_waitcnt lgkmcnt(0)" ::: "memory");
        #pragma unroll
        for (int j32 = 0; j32 < 2; ++j32){
          bf16x8 pf = *(const bf16x8*)((char*)Ps[wid] + lrow * 128 +
                        ((j32 * 64 + g8 * 16) ^ ((lrow & 7) << 4)));
          #pragma unroll
          for (int dcb = 0; dcb < 8; ++dcb){
            int d = dcb * 16 + lrow;
            bf16x8 vf = *(const bf16x8*)((char*)VTs + d * 128 +
                          ((j32 * 64 + g8 * 16) ^ ((((d >> 3) ^ d) & 7) << 4)));
            O[dcb] = __builtin_amdgcn_mfma_f32_16x16x32_bf16(vf, pf, O[dcb], 0, 0, 0);
          }
        }
      }
    }
    float inv = 1.0f / lsum;
    #pragma unroll
    for (int dcb = 0; dcb < 8; ++dcb){
      bf16x4 w4;
      #pragma unroll
      for (int r = 0; r < 4; ++r) w4[r] = (short)f2bf(O[dcb][r] * inv);
      *(bf16x4*)(ob + ((size_t)(b * NT + tq)) * (NH * ND) + h * ND + dcb * 16 + g8 * 4) = w4;
    }
  }
}

// ---------------------------------------------------------------------------
extern "C" void kernel_launch(void* const* d_in, const int* in_sizes, int n_in,
                              void* d_out, int out_size, void* d_ws, size_t ws_size,
                              hipStream_t stream){
  const float* x  = (const float*)d_in[0];
  const float* wq = (const float*)d_in[1];
  const float* wk = (const float*)d_in[2];
  const float* wv = (const float*)d_in[3];
  const float* wo = (const float*)d_in[4];
  const float* gq = (const float*)d_in[5];
  const float* bq = (const float*)d_in[6];
  const float* gk = (const float*)d_in[7];
  const float* bk = (const float*)d_in[8];

  char* ws = (char*)d_ws;
  short* xb   = (short*)(ws);                      // 16,777,216 B
  short* wT   = (short*)(ws + 16777216);           // 33,554,432 B (q,k,v,o ^T)
  short* qkvb = (short*)(ws + 50331648);           // 50,331,648 B (q|k|v bf16 BHTD)
  short* qkn  = (short*)(ws + 100663296);          // 33,554,432 B (qn|kn)
  short* ob   = (short*)(ws + 134217728);          // 16,777,216 B
  float* ctab = (float*)(ws + 150994944);          // 524,288 B
  float* stab = (float*)(ws + 151519232);          // 524,288 B

  (void)hipFuncSetAttribute((const void*)gemm256_k,
                            hipFuncAttributeMaxDynamicSharedMemorySize, 131072);

  rope_table_k<<<dim3(2048), dim3(64), 0, stream>>>(ctab, stab);
  cast_x_k<<<dim3(8192), dim3(256), 0, stream>>>(x, xb);
  transpose_w_k<<<dim3(64, 64, 4), dim3(256), 0, stream>>>(wq, wk, wv, wo, wT);
  gemm256_k<<<dim3(384), dim3(512), 131072, stream>>>(xb, wT, qkvb);
  norm_rope_k<<<dim3(16384, 2), dim3(256), 0, stream>>>(qkvb, qkn, gq, bq, gk, bk, ctab, stab);
  attn_k<<<dim3(16, 32), dim3(256), 0, stream>>>(qkn, qkn + 8388608,
                                                 qkvb + 2 * (size_t)8388608, ob);
  gemm_bt_k<<<dim3(32, 16), dim3(256), 0, stream>>>(ob, wT + 3 * (size_t)4194304,
                                                    (float*)d_out, 2048);
}

// Round 6
// 320.990 us; speedup vs baseline: 1.0877x; 1.0877x over previous
//
#include <hip/hip_runtime.h>

// ---------------------------------------------------------------------------
// Fused MHA: B=2, T=2048, M=2048, H=16, D=128, causal, qk-centered-RMS-norm,
// half-split rotary, QK_SCALE = 1/D.
// Pipeline: cast/transposes -> QKV GEMM (256^2 8-wave, 4-phase schedule with
// counted staggered vmcnt) -> norm+rope -> flash attn -> out GEMM (fp32 out).
// ---------------------------------------------------------------------------

#define NB 2
#define NT 2048
#define NM 2048
#define NH 16
#define ND 128

typedef __attribute__((ext_vector_type(4))) float f32x4;
typedef __attribute__((ext_vector_type(8))) short bf16x8;
typedef __attribute__((ext_vector_type(4))) short bf16x4;

#define AS1 __attribute__((address_space(1)))
#define AS3 __attribute__((address_space(3)))

__device__ __forceinline__ unsigned short f2bf(float f){
  unsigned int u = __float_as_uint(f);
  u = (u + 0x7fffu + ((u >> 16) & 1u)) >> 16;   // RNE
  return (unsigned short)u;
}
__device__ __forceinline__ float bf2f(short s){
  return __uint_as_float(((unsigned int)(unsigned short)s) << 16);
}
__device__ __forceinline__ float wredsum(float v){
  #pragma unroll
  for (int m = 1; m < 64; m <<= 1) v += __shfl_xor(v, m);
  return v;
}
__device__ __forceinline__ void gload_lds16(const void* g, void* l){
  __builtin_amdgcn_global_load_lds((const AS1 void*)g, (AS3 void*)l, 16, 0, 0);
}

// ---------------- rope cos/sin table: [T][64] each --------------------------
__global__ __launch_bounds__(64) void rope_table_k(float* ctab, float* stab){
  int t = blockIdx.x, i = threadIdx.x;
  float freq = __expf(-(float)i * (9.210340371976184f / 64.0f)); // ln(10000)
  float ang = (float)t * freq;
  ctab[t * 64 + i] = cosf(ang);
  stab[t * 64 + i] = sinf(ang);
}

// ---------------- cast x fp32 -> bf16 --------------------------------------
__global__ __launch_bounds__(256) void cast_x_k(const float* __restrict__ x,
                                                short* __restrict__ xb){
  size_t gid = (size_t)blockIdx.x * 256 + threadIdx.x;
  float4 v = *(const float4*)(x + gid * 4);
  bf16x4 o;
  o[0] = (short)f2bf(v.x); o[1] = (short)f2bf(v.y);
  o[2] = (short)f2bf(v.z); o[3] = (short)f2bf(v.w);
  *(bf16x4*)(xb + gid * 4) = o;
}

// ------------- transpose weights fp32 [K][N] -> bf16 [N][K] ----------------
__global__ __launch_bounds__(256) void transpose_w_k(const float* __restrict__ wq,
                                                     const float* __restrict__ wk,
                                                     const float* __restrict__ wv,
                                                     const float* __restrict__ wo,
                                                     short* __restrict__ wT){
  __shared__ float tl[32][33];
  int z = blockIdx.z;
  const float* src = (z == 0) ? wq : (z == 1) ? wk : (z == 2) ? wv : wo;
  short* dst = wT + (size_t)z * 2048 * 2048;
  int n0 = blockIdx.x * 32, k0 = blockIdx.y * 32;
  int cx = threadIdx.x & 31, ry = threadIdx.x >> 5; // 0..7
  #pragma unroll
  for (int p = 0; p < 4; ++p)
    tl[ry + 8 * p][cx] = src[(size_t)(k0 + ry + 8 * p) * 2048 + n0 + cx];
  __syncthreads();
  #pragma unroll
  for (int p = 0; p < 4; ++p)
    dst[(size_t)(n0 + ry + 8 * p) * 2048 + k0 + cx] =
        (short)f2bf(tl[cx][ry + 8 * p]);
}

// ---------------------------------------------------------------------------
// QKV GEMM: C[4096 x 6144] = A[4096 x 2048] * B^T[6144 x 2048] (bf16)
// 256x256 tile, BK=64, 8 waves (2M x 4N), 512 threads, 128 KiB dynamic LDS.
// 4 phases per K-tile, one C-quadrant each:
//   phase p: {vmcnt(4) [p<3]; barrier; 12 ds_reads; stage 1 unit of kt+1;
//             barrier; setprio(1); 16 MFMA; setprio(0)}
// Staging units match phase consumption (A-unit(qm) = quarters {qm,qm+2};
// B-unit(qn) = stripes w*64+qn*32) issued in order A0,B0,B1,A1 -> every
// waited-on unit is >=3 phases old. vmcnt never 0 in the main loop.
// ---------------------------------------------------------------------------
#define NKT 32   // 2048 / 64
__global__ __launch_bounds__(512, 2) void gemm256_k(const short* __restrict__ A,
                                                    const short* __restrict__ Bt,
                                                    short* __restrict__ Cq){
  extern __shared__ char lds[];
  const int tid = threadIdx.x;
  const int wid = tid >> 6, lane = tid & 63;
  const int lrow = lane & 15, g8 = lane >> 4;
  const int wm = wid >> 2, wn = wid & 3;
  const int Kdim = 2048;

  // XCD-aware bijective swizzle over 384 blocks (384 % 8 == 0)
  int bid = blockIdx.x;
  int s = (bid & 7) * 48 + (bid >> 3);
  const int bx = s & 15;        // 16 m-tiles
  const int by = s >> 4;        // 24 n-tiles
  const int m0 = bx * 256, n0 = by * 256;

  const int r8 = lane >> 3;                  // row within 8-row DMA block
  const int gcol = ((lane & 7) ^ r8) * 8;    // inverse-swizzled source granule

  f32x4 acc[8][4] = {};

  // A-unit(qm): tile rows {qm*64..+63} u {128+qm*64..+63}
  auto STAGE_A = [&](int c2, int kt2, int qm){
    #pragma unroll
    for (int l = 0; l < 2; ++l){
      int trow = (qm + 2 * l) * 64 + wid * 8;
      gload_lds16(A + (size_t)(m0 + trow + r8) * Kdim + kt2 * 64 + gcol,
                  lds + c2 * 32768 + trow * 128);
    }
  };
  // B-unit(qn): tile rows {w*64 + qn*32 .. +31, w=0..3}
  auto STAGE_B = [&](int c2, int kt2, int qn){
    #pragma unroll
    for (int l = 0; l < 2; ++l){
      int trow = (wid >> 1) * 64 + qn * 32 + (wid & 1) * 16 + l * 8;
      gload_lds16(Bt + (size_t)(n0 + trow + r8) * Kdim + kt2 * 64 + gcol,
                  lds + 65536 + c2 * 32768 + trow * 128);
    }
  };
  auto ldA = [&](int c, int mi, int kk) -> bf16x8 {
    int row = mi * 16 + lrow;
    int col = (kk * 64 + g8 * 16) ^ ((lrow & 7) << 4);
    return *(const bf16x8*)(lds + c * 32768 + wm * 16384 + row * 128 + col);
  };
  auto ldB = [&](int c, int ni, int kk) -> bf16x8 {
    int row = (wn & 1) * 64 + ni * 16 + lrow;
    int col = (kk * 64 + g8 * 16) ^ ((lrow & 7) << 4);
    return *(const bf16x8*)(lds + 65536 + c * 32768 + (wn >> 1) * 16384 + row * 128 + col);
  };

  // prologue: stage tile 0 in unit order A0,B0,B1,A1
  STAGE_A(0, 0, 0);
  STAGE_B(0, 0, 0);
  STAGE_B(0, 0, 1);
  STAGE_A(0, 0, 1);

  for (int kt = 0; kt < NKT; ++kt){
    const int c = kt & 1;
    const bool nl = (kt + 1 < NKT);
    #pragma unroll
    for (int q = 0; q < 4; ++q){
      const int qm = q >> 1, qn = q & 1;
      if (nl){
        if (q < 3) asm volatile("s_waitcnt vmcnt(4)" ::: "memory");
      } else {
        if (q == 0) asm volatile("s_waitcnt vmcnt(0)" ::: "memory");
      }
      __builtin_amdgcn_s_barrier();          // publish this phase's data
      bf16x8 af[4][2], bfv[2][2];
      #pragma unroll
      for (int i = 0; i < 4; ++i)
        #pragma unroll
        for (int kk = 0; kk < 2; ++kk)
          af[i][kk] = ldA(c, qm * 4 + i, kk);
      #pragma unroll
      for (int j = 0; j < 2; ++j)
        #pragma unroll
        for (int kk = 0; kk < 2; ++kk)
          bfv[j][kk] = ldB(c, qn * 2 + j, kk);
      if (nl){
        if (q == 0)      STAGE_A(c ^ 1, kt + 1, 0);
        else if (q == 1) STAGE_B(c ^ 1, kt + 1, 0);
        else if (q == 2) STAGE_B(c ^ 1, kt + 1, 1);
        else             STAGE_A(c ^ 1, kt + 1, 1);
      }
      __builtin_amdgcn_s_barrier();          // cluster LDS service
      __builtin_amdgcn_s_setprio(1);
      #pragma unroll
      for (int kk = 0; kk < 2; ++kk)
        #pragma unroll
        for (int i = 0; i < 4; ++i)
          #pragma unroll
          for (int j = 0; j < 2; ++j)
            acc[qm * 4 + i][qn * 2 + j] = __builtin_amdgcn_mfma_f32_16x16x32_bf16(
                af[i][kk], bfv[j][kk], acc[qm * 4 + i][qn * 2 + j], 0, 0, 0);
      __builtin_amdgcn_s_setprio(0);
    }
  }

  // ---- scatter epilogue: bf16 into q|k|v [B,H,T,D] ----
  #pragma unroll
  for (int mi = 0; mi < 8; ++mi){
    int rowb = m0 + wm * 128 + mi * 16 + g8 * 4;
    #pragma unroll
    for (int ni = 0; ni < 4; ++ni){
      int col = n0 + wn * 64 + ni * 16 + lrow;
      int tsel = col >> 11;
      int hd = col & 2047;
      int hh = hd >> 7, d = hd & 127;
      short* dst = Cq + (size_t)tsel * (NB * NH * NT * ND);
      f32x4 a = acc[mi][ni];
      #pragma unroll
      for (int r = 0; r < 4; ++r){
        int bt = rowb + r;
        int b = bt >> 11, t = bt & 2047;
        dst[(((size_t)(b * NH + hh)) * NT + t) * ND + d] = (short)f2bf(a[r]);
      }
    }
  }
}

// ---------------- out-proj GEMM (128^2, double-buffered, 1-barrier) --------
// C[4096 x 2048] = A[4096 x K] * B^T[2048 x K], fp32 row-major out
__global__ __launch_bounds__(256) void gemm_bt_k(const short* __restrict__ A,
                                                 const short* __restrict__ Bt,
                                                 float* __restrict__ Cout,
                                                 int Kdim){
  __shared__ short As[2][128 * 32];
  __shared__ short Bs[2][128 * 32];
  const int tid = threadIdx.x;
  const int wid = tid >> 6, lane = tid & 63;
  const int lrow = lane & 15, g8 = lane >> 4;
  const int wm = wid >> 1, wn = wid & 1;
  const int m0 = blockIdx.x * 128, n0 = blockIdx.y * 128;
  f32x4 acc[4][4] = {};
  const int srow = lane >> 2;
  const int skcol = (lane & 3) * 8;

  auto STAGE = [&](int c, int kt){
    #pragma unroll
    for (int i = 0; i < 2; ++i){
      int inst = wid * 2 + i;
      int r = inst * 16 + srow;
      const short* sa = A  + (size_t)(m0 + r) * Kdim + kt + skcol;
      const short* sb = Bt + (size_t)(n0 + r) * Kdim + kt + skcol;
      gload_lds16(sa, (char*)As[c] + inst * 1024);
      gload_lds16(sb, (char*)Bs[c] + inst * 1024);
    }
  };

  STAGE(0, 0);
  const int nkt = Kdim >> 5;
  for (int it = 0; it < nkt; ++it){
    const int c = it & 1;
    asm volatile("s_waitcnt vmcnt(0)" ::: "memory");
    __builtin_amdgcn_s_barrier();
    if (it + 1 < nkt) STAGE(c ^ 1, (it + 1) << 5);

    bf16x8 af[4], bfv[4];
    #pragma unroll
    for (int mi = 0; mi < 4; ++mi)
      af[mi] = *(const bf16x8*)&As[c][(wm * 64 + mi * 16 + lrow) * 32 + g8 * 8];
    #pragma unroll
    for (int ni = 0; ni < 4; ++ni)
      bfv[ni] = *(const bf16x8*)&Bs[c][(wn * 64 + ni * 16 + lrow) * 32 + g8 * 8];
    #pragma unroll
    for (int mi = 0; mi < 4; ++mi)
      #pragma unroll
      for (int ni = 0; ni < 4; ++ni)
        acc[mi][ni] = __builtin_amdgcn_mfma_f32_16x16x32_bf16(
            af[mi], bfv[ni], acc[mi][ni], 0, 0, 0);
  }

  #pragma unroll
  for (int mi = 0; mi < 4; ++mi){
    int rowb = m0 + wm * 64 + mi * 16 + g8 * 4;
    #pragma unroll
    for (int ni = 0; ni < 4; ++ni){
      int col = n0 + wn * 64 + ni * 16 + lrow;
      f32x4 a = acc[mi][ni];
      #pragma unroll
      for (int r = 0; r < 4; ++r)
        Cout[(size_t)(rowb + r) * 2048 + col] = a[r];
    }
  }
}

// -------------- centered RMS norm + rotary (q and k) -----------------------
__global__ __launch_bounds__(256) void norm_rope_k(const short* __restrict__ qkv,
                                                   short* __restrict__ outp,
                                                   const float* __restrict__ gq,
                                                   const float* __restrict__ bq,
                                                   const float* __restrict__ gk,
                                                   const float* __restrict__ bk,
                                                   const float* __restrict__ ctab,
                                                   const float* __restrict__ stab){
  int which = blockIdx.y;
  const short* src = qkv + (size_t)which * (NB * NH * NT * ND);
  short* dst = outp + (size_t)which * (NB * NH * NT * ND);
  const float* g = which ? gk : gq;
  const float* bb = which ? bk : bq;
  int wid = threadIdx.x >> 6, lane = threadIdx.x & 63;
  size_t row = (size_t)blockIdx.x * 4 + wid;  // over B*H*T
  int h = (int)((row >> 11) & 15);
  int t = (int)(row & 2047);
  const short* rp = src + row * ND;
  float v0 = bf2f(rp[lane]), v1 = bf2f(rp[lane + 64]);
  float mean = wredsum(v0 + v1) * (1.0f / 128.0f);
  float c0 = v0 - mean, c1 = v1 - mean;
  float ms = wredsum(c0 * c0 + c1 * c1) * (1.0f / 128.0f);
  float rstd = rsqrtf(ms + 1e-6f);
  float n0 = c0 * rstd * (1.0f + g[h * ND + lane]) + bb[h * ND + lane];
  float n1 = c1 * rstd * (1.0f + g[h * ND + lane + 64]) + bb[h * ND + lane + 64];
  float co = ctab[t * 64 + lane], si = stab[t * 64 + lane];
  short* wp = dst + row * ND;
  wp[lane]      = (short)f2bf(n0 * co - n1 * si);
  wp[lane + 64] = (short)f2bf(n0 * si + n1 * co);
}

// ---------------- flash attention, causal (R4 version) ---------------------
__global__ __launch_bounds__(256) void attn_k(const short* __restrict__ qn,
                                              const short* __restrict__ kn,
                                              const short* __restrict__ vsrc,
                                              short* __restrict__ ob){
  __shared__ short Ks[64 * 128];
  __shared__ short VTs[128 * 64];
  __shared__ short Ps[4][16 * 64];
  const int tid = threadIdx.x;
  const int wid = tid >> 6, lane = tid & 63;
  const int lrow = lane & 15, g8 = lane >> 4;
  const int bh = blockIdx.y;
  const int b = bh >> 4, h = bh & 15;
  const size_t base = (size_t)bh * NT * ND;

  for (int pass = 0; pass < 2; ++pass){
    const int qt = pass ? (31 - (int)blockIdx.x) : (int)blockIdx.x;
    const int t0 = qt * 64;
    const int tq = t0 + wid * 16 + lrow;
    bf16x8 qf[4];
    #pragma unroll
    for (int dc = 0; dc < 4; ++dc)
      qf[dc] = *(const bf16x8*)(qn + base + (size_t)tq * ND + dc * 32 + g8 * 8);
    f32x4 O[8] = {};
    float m = -3e38f, lsum = 0.0f;
    const int ntiles = qt + 1;

    for (int jb = 0; jb < ntiles; ++jb){
      __syncthreads();
      #pragma unroll
      for (int p = 0; p < 4; ++p){
        int r = (tid >> 4) + p * 16;
        int c = tid & 15;
        bf16x8 kv = *(const bf16x8*)(kn + base + (size_t)(jb * 64 + r) * ND + c * 8);
        *(bf16x8*)((char*)Ks + r * 256 + ((c * 16) ^ ((r & 7) << 4))) = kv;
      }
      #pragma unroll
      for (int p = 0; p < 4; ++p){
        int jr = (tid >> 4) + p * 16;
        int d0 = (tid & 15) * 8;
        bf16x8 vv = *(const bf16x8*)(vsrc + base + (size_t)(jb * 64 + jr) * ND + d0);
        #pragma unroll
        for (int i = 0; i < 8; ++i){
          int d = d0 + i;
          *(short*)((char*)VTs + d * 128 +
                    ((jr * 2) ^ ((((d >> 3) ^ d) & 7) << 4))) = vv[i];
        }
      }
      __syncthreads();

      if (jb * 64 <= t0 + wid * 16 + 15){
        f32x4 st[4] = {};
        #pragma unroll
        for (int dc = 0; dc < 4; ++dc)
          #pragma unroll
          for (int js = 0; js < 4; ++js){
            int jl = js * 16 + lrow;
            bf16x8 kf = *(const bf16x8*)((char*)Ks + jl * 256 +
                          ((dc * 64 + g8 * 16) ^ ((jl & 7) << 4)));
            st[js] = __builtin_amdgcn_mfma_f32_16x16x32_bf16(kf, qf[dc], st[js], 0, 0, 0);
          }
        float mx = -3e38f;
        #pragma unroll
        for (int js = 0; js < 4; ++js)
          #pragma unroll
          for (int r = 0; r < 4; ++r){
            float s = st[js][r] * (1.0f / 128.0f);
            int j = jb * 64 + js * 16 + g8 * 4 + r;
            if (j > tq) s = -3e38f;
            st[js][r] = s;
            mx = fmaxf(mx, s);
          }
        mx = fmaxf(mx, __shfl_xor(mx, 16));
        mx = fmaxf(mx, __shfl_xor(mx, 32));
        float mnew = fmaxf(m, mx);
        float fac = __expf(m - mnew);
        m = mnew;
        lsum *= fac;
        #pragma unroll
        for (int dcb = 0; dcb < 8; ++dcb) O[dcb] *= fac;
        float ps = 0.0f;
        #pragma unroll
        for (int js = 0; js < 4; ++js)
          #pragma unroll
          for (int r = 0; r < 4; ++r){
            float p = __expf(st[js][r] - mnew);
            ps += p;
            int jl = js * 16 + g8 * 4 + r;
            *(short*)((char*)Ps[wid] + lrow * 128 +
                      ((jl * 2) ^ ((lrow & 7) << 4))) = (short)f2bf(p);
          }
        ps += __shfl_xor(ps, 16);
        ps += __shfl_xor(ps, 32);
        lsum += ps;
        asm volatile("s_waitcnt lgkmcnt(0)" ::: "memory");
        #pragma unroll
        for (int j32 = 0; j32 < 2; ++j32){
          bf16x8 pf = *(const bf16x8*)((char*)Ps[wid] + lrow * 128 +
                        ((j32 * 64 + g8 * 16) ^ ((lrow & 7) << 4)));
          #pragma unroll
          for (int dcb = 0; dcb < 8; ++dcb){
            int d = dcb * 16 + lrow;
            bf16x8 vf = *(const bf16x8*)((char*)VTs + d * 128 +
                          ((j32 * 64 + g8 * 16) ^ ((((d >> 3) ^ d) & 7) << 4)));
            O[dcb] = __builtin_amdgcn_mfma_f32_16x16x32_bf16(vf, pf, O[dcb], 0, 0, 0);
          }
        }
      }
    }
    float inv = 1.0f / lsum;
    #pragma unroll
    for (int dcb = 0; dcb < 8; ++dcb){
      bf16x4 w4;
      #pragma unroll
      for (int r = 0; r < 4; ++r) w4[r] = (short)f2bf(O[dcb][r] * inv);
      *(bf16x4*)(ob + ((size_t)(b * NT + tq)) * (NH * ND) + h * ND + dcb * 16 + g8 * 4) = w4;
    }
  }
}

// ---------------------------------------------------------------------------
extern "C" void kernel_launch(void* const* d_in, const int* in_sizes, int n_in,
                              void* d_out, int out_size, void* d_ws, size_t ws_size,
                              hipStream_t stream){
  const float* x  = (const float*)d_in[0];
  const float* wq = (const float*)d_in[1];
  const float* wk = (const float*)d_in[2];
  const float* wv = (const float*)d_in[3];
  const float* wo = (const float*)d_in[4];
  const float* gq = (const float*)d_in[5];
  const float* bq = (const float*)d_in[6];
  const float* gk = (const float*)d_in[7];
  const float* bk = (const float*)d_in[8];

  char* ws = (char*)d_ws;
  short* xb   = (short*)(ws);                      // 16,777,216 B
  short* wT   = (short*)(ws + 16777216);           // 33,554,432 B (q,k,v,o ^T)
  short* qkvb = (short*)(ws + 50331648);           // 50,331,648 B (q|k|v bf16 BHTD)
  short* qkn  = (short*)(ws + 100663296);          // 33,554,432 B (qn|kn)
  short* ob   = (short*)(ws + 134217728);          // 16,777,216 B
  float* ctab = (float*)(ws + 150994944);          // 524,288 B
  float* stab = (float*)(ws + 151519232);          // 524,288 B

  (void)hipFuncSetAttribute((const void*)gemm256_k,
                            hipFuncAttributeMaxDynamicSharedMemorySize, 131072);

  rope_table_k<<<dim3(2048), dim3(64), 0, stream>>>(ctab, stab);
  cast_x_k<<<dim3(8192), dim3(256), 0, stream>>>(x, xb);
  transpose_w_k<<<dim3(64, 64, 4), dim3(256), 0, stream>>>(wq, wk, wv, wo, wT);
  gemm256_k<<<dim3(384), dim3(512), 131072, stream>>>(xb, wT, qkvb);
  norm_rope_k<<<dim3(16384, 2), dim3(256), 0, stream>>>(qkvb, qkn, gq, bq, gk, bk, ctab, stab);
  attn_k<<<dim3(16, 32), dim3(256), 0, stream>>>(qkn, qkn + 8388608,
                                                 qkvb + 2 * (size_t)8388608, ob);
  gemm_bt_k<<<dim3(32, 16), dim3(256), 0, stream>>>(ob, wT + 3 * (size_t)4194304,
                                                    (float*)d_out, 2048);
}

// Round 7
// 307.592 us; speedup vs baseline: 1.1351x; 1.0436x over previous
//
#include <hip/hip_runtime.h>

// ---------------------------------------------------------------------------
// Fused MHA: B=2, T=2048, M=2048, H=16, D=128, causal, qk-centered-RMS-norm,
// half-split rotary, QK_SCALE = 1/D.
// Pipeline: cast/transposes -> QKV GEMM (256^2 8-wave, R4 minimal-sync loop;
// V written pre-transposed) -> norm+rope -> flash attn (gload_lds staging,
// 2-phase prefetch, dbuf LDS) -> out GEMM (fp32 out).
// ---------------------------------------------------------------------------

#define NB 2
#define NT 2048
#define NM 2048
#define NH 16
#define ND 128

typedef __attribute__((ext_vector_type(4))) float f32x4;
typedef __attribute__((ext_vector_type(8))) short bf16x8;
typedef __attribute__((ext_vector_type(4))) short bf16x4;

#define AS1 __attribute__((address_space(1)))
#define AS3 __attribute__((address_space(3)))

__device__ __forceinline__ unsigned short f2bf(float f){
  unsigned int u = __float_as_uint(f);
  u = (u + 0x7fffu + ((u >> 16) & 1u)) >> 16;   // RNE
  return (unsigned short)u;
}
__device__ __forceinline__ float bf2f(short s){
  return __uint_as_float(((unsigned int)(unsigned short)s) << 16);
}
__device__ __forceinline__ float wredsum(float v){
  #pragma unroll
  for (int m = 1; m < 64; m <<= 1) v += __shfl_xor(v, m);
  return v;
}
__device__ __forceinline__ void gload_lds16(const void* g, void* l){
  __builtin_amdgcn_global_load_lds((const AS1 void*)g, (AS3 void*)l, 16, 0, 0);
}

// ---------------- rope cos/sin table: [T][64] each --------------------------
__global__ __launch_bounds__(64) void rope_table_k(float* ctab, float* stab){
  int t = blockIdx.x, i = threadIdx.x;
  float freq = __expf(-(float)i * (9.210340371976184f / 64.0f)); // ln(10000)
  float ang = (float)t * freq;
  ctab[t * 64 + i] = cosf(ang);
  stab[t * 64 + i] = sinf(ang);
}

// ---------------- cast x fp32 -> bf16 --------------------------------------
__global__ __launch_bounds__(256) void cast_x_k(const float* __restrict__ x,
                                                short* __restrict__ xb){
  size_t gid = (size_t)blockIdx.x * 256 + threadIdx.x;
  float4 v = *(const float4*)(x + gid * 4);
  bf16x4 o;
  o[0] = (short)f2bf(v.x); o[1] = (short)f2bf(v.y);
  o[2] = (short)f2bf(v.z); o[3] = (short)f2bf(v.w);
  *(bf16x4*)(xb + gid * 4) = o;
}

// ------------- transpose weights fp32 [K][N] -> bf16 [N][K] ----------------
__global__ __launch_bounds__(256) void transpose_w_k(const float* __restrict__ wq,
                                                     const float* __restrict__ wk,
                                                     const float* __restrict__ wv,
                                                     const float* __restrict__ wo,
                                                     short* __restrict__ wT){
  __shared__ float tl[32][33];
  int z = blockIdx.z;
  const float* src = (z == 0) ? wq : (z == 1) ? wk : (z == 2) ? wv : wo;
  short* dst = wT + (size_t)z * 2048 * 2048;
  int n0 = blockIdx.x * 32, k0 = blockIdx.y * 32;
  int cx = threadIdx.x & 31, ry = threadIdx.x >> 5; // 0..7
  #pragma unroll
  for (int p = 0; p < 4; ++p)
    tl[ry + 8 * p][cx] = src[(size_t)(k0 + ry + 8 * p) * 2048 + n0 + cx];
  __syncthreads();
  #pragma unroll
  for (int p = 0; p < 4; ++p)
    dst[(size_t)(n0 + ry + 8 * p) * 2048 + k0 + cx] =
        (short)f2bf(tl[cx][ry + 8 * p]);
}

// ---------------------------------------------------------------------------
// QKV GEMM: C[4096 x 6144] = A[4096 x 2048] * B^T[6144 x 2048] (bf16)
// 256x256 tile, BK=64, 8 waves (2M x 4N), 512 threads, 128 KiB dynamic LDS.
// R4 minimal-sync K-loop (best measured: 118.7 us). V scattered TRANSPOSED.
// ---------------------------------------------------------------------------
#define NKT 32   // 2048 / 64
__global__ __launch_bounds__(512, 2) void gemm256_k(const short* __restrict__ A,
                                                    const short* __restrict__ Bt,
                                                    short* __restrict__ Cq){
  extern __shared__ char lds[];
  const int tid = threadIdx.x;
  const int wid = tid >> 6, lane = tid & 63;
  const int lrow = lane & 15, g8 = lane >> 4;
  const int wm = wid >> 2, wn = wid & 3;
  const int Kdim = 2048;

  // XCD-aware bijective swizzle over 384 blocks (384 % 8 == 0)
  int bid = blockIdx.x;
  int s = (bid & 7) * 48 + (bid >> 3);
  const int bx = s & 15;        // 16 m-tiles
  const int by = s >> 4;        // 24 n-tiles
  const int m0 = bx * 256, n0 = by * 256;

  const int r8 = lane >> 3;
  const int gcol = ((lane & 7) ^ r8) * 8;           // inverse-swizzled source
  const short* Ab = A  + (size_t)(m0 + wid * 8 + r8) * Kdim + gcol;
  const short* Bb = Bt + (size_t)(n0 + wid * 8 + r8) * Kdim + gcol;

  f32x4 acc[8][4] = {};

  auto STAGE = [&](int c, int kt){
    #pragma unroll
    for (int h = 0; h < 2; ++h)
      #pragma unroll
      for (int l = 0; l < 2; ++l){
        size_t roff = (size_t)(h * 128 + l * 64) * Kdim + kt * 64;
        char* la = lds + c * 32768 + h * 16384 + l * 8192 + wid * 1024;
        gload_lds16(Ab + roff, la);
        gload_lds16(Bb + roff, la + 65536);
      }
  };
  auto ldA = [&](int c, int mi, int kk) -> bf16x8 {
    int row = mi * 16 + lrow;
    int col = (kk * 64 + g8 * 16) ^ ((lrow & 7) << 4);
    return *(const bf16x8*)(lds + c * 32768 + wm * 16384 + row * 128 + col);
  };
  auto ldB = [&](int c, int ni, int kk) -> bf16x8 {
    int row = (wn & 1) * 64 + ni * 16 + lrow;
    int col = (kk * 64 + g8 * 16) ^ ((lrow & 7) << 4);
    return *(const bf16x8*)(lds + 65536 + c * 32768 + (wn >> 1) * 16384 + row * 128 + col);
  };

  STAGE(0, 0);   // prologue

  for (int kt = 0; kt < NKT; ++kt){
    const int c = kt & 1;
    asm volatile("s_waitcnt vmcnt(0)" ::: "memory");
    __builtin_amdgcn_s_barrier();
    if (kt + 1 < NKT) STAGE(c ^ 1, kt + 1);

    #pragma unroll
    for (int kk = 0; kk < 2; ++kk){
      bf16x8 bfr[4];
      #pragma unroll
      for (int ni = 0; ni < 4; ++ni) bfr[ni] = ldB(c, ni, kk);
      #pragma unroll
      for (int mh = 0; mh < 2; ++mh){
        bf16x8 afr[4];
        #pragma unroll
        for (int mi = 0; mi < 4; ++mi) afr[mi] = ldA(c, mh * 4 + mi, kk);
        #pragma unroll
        for (int mi = 0; mi < 4; ++mi)
          #pragma unroll
          for (int ni = 0; ni < 4; ++ni)
            acc[mh * 4 + mi][ni] = __builtin_amdgcn_mfma_f32_16x16x32_bf16(
                afr[mi], bfr[ni], acc[mh * 4 + mi][ni], 0, 0, 0);
      }
    }
  }

  // ---- scatter epilogue: q,k bf16 [B,H,T,D]; v bf16 TRANSPOSED [B,H,D,T] --
  #pragma unroll
  for (int mi = 0; mi < 8; ++mi){
    int rowb = m0 + wm * 128 + mi * 16 + g8 * 4;
    #pragma unroll
    for (int ni = 0; ni < 4; ++ni){
      int col = n0 + wn * 64 + ni * 16 + lrow;
      int tsel = col >> 11;
      int hd = col & 2047;
      int hh = hd >> 7, d = hd & 127;
      short* dst = Cq + (size_t)tsel * (NB * NH * NT * ND);
      f32x4 a = acc[mi][ni];
      if (tsel == 2){
        int b = rowb >> 11, t0 = rowb & 2047;   // 4 consecutive t, same b
        bf16x4 w4;
        #pragma unroll
        for (int r = 0; r < 4; ++r) w4[r] = (short)f2bf(a[r]);
        *(bf16x4*)&dst[(((size_t)(b * NH + hh)) * ND + d) * NT + t0] = w4;
      } else {
        #pragma unroll
        for (int r = 0; r < 4; ++r){
          int bt = rowb + r;
          int b = bt >> 11, t = bt & 2047;
          dst[(((size_t)(b * NH + hh)) * NT + t) * ND + d] = (short)f2bf(a[r]);
        }
      }
    }
  }
}

// ---------------- out-proj GEMM (128^2, double-buffered, 1-barrier) --------
// C[4096 x 2048] = A[4096 x K] * B^T[2048 x K], fp32 row-major out
__global__ __launch_bounds__(256) void gemm_bt_k(const short* __restrict__ A,
                                                 const short* __restrict__ Bt,
                                                 float* __restrict__ Cout,
                                                 int Kdim){
  __shared__ short As[2][128 * 32];
  __shared__ short Bs[2][128 * 32];
  const int tid = threadIdx.x;
  const int wid = tid >> 6, lane = tid & 63;
  const int lrow = lane & 15, g8 = lane >> 4;
  const int wm = wid >> 1, wn = wid & 1;
  const int m0 = blockIdx.x * 128, n0 = blockIdx.y * 128;
  f32x4 acc[4][4] = {};
  const int srow = lane >> 2;
  const int skcol = (lane & 3) * 8;

  auto STAGE = [&](int c, int kt){
    #pragma unroll
    for (int i = 0; i < 2; ++i){
      int inst = wid * 2 + i;
      int r = inst * 16 + srow;
      const short* sa = A  + (size_t)(m0 + r) * Kdim + kt + skcol;
      const short* sb = Bt + (size_t)(n0 + r) * Kdim + kt + skcol;
      gload_lds16(sa, (char*)As[c] + inst * 1024);
      gload_lds16(sb, (char*)Bs[c] + inst * 1024);
    }
  };

  STAGE(0, 0);
  const int nkt = Kdim >> 5;
  for (int it = 0; it < nkt; ++it){
    const int c = it & 1;
    asm volatile("s_waitcnt vmcnt(0)" ::: "memory");
    __builtin_amdgcn_s_barrier();
    if (it + 1 < nkt) STAGE(c ^ 1, (it + 1) << 5);

    bf16x8 af[4], bfv[4];
    #pragma unroll
    for (int mi = 0; mi < 4; ++mi)
      af[mi] = *(const bf16x8*)&As[c][(wm * 64 + mi * 16 + lrow) * 32 + g8 * 8];
    #pragma unroll
    for (int ni = 0; ni < 4; ++ni)
      bfv[ni] = *(const bf16x8*)&Bs[c][(wn * 64 + ni * 16 + lrow) * 32 + g8 * 8];
    #pragma unroll
    for (int mi = 0; mi < 4; ++mi)
      #pragma unroll
      for (int ni = 0; ni < 4; ++ni)
        acc[mi][ni] = __builtin_amdgcn_mfma_f32_16x16x32_bf16(
            af[mi], bfv[ni], acc[mi][ni], 0, 0, 0);
  }

  #pragma unroll
  for (int mi = 0; mi < 4; ++mi){
    int rowb = m0 + wm * 64 + mi * 16 + g8 * 4;
    #pragma unroll
    for (int ni = 0; ni < 4; ++ni){
      int col = n0 + wn * 64 + ni * 16 + lrow;
      f32x4 a = acc[mi][ni];
      #pragma unroll
      for (int r = 0; r < 4; ++r)
        Cout[(size_t)(rowb + r) * 2048 + col] = a[r];
    }
  }
}

// -------------- centered RMS norm + rotary (q and k) -----------------------
__global__ __launch_bounds__(256) void norm_rope_k(const short* __restrict__ qkv,
                                                   short* __restrict__ outp,
                                                   const float* __restrict__ gq,
                                                   const float* __restrict__ bq,
                                                   const float* __restrict__ gk,
                                                   const float* __restrict__ bk,
                                                   const float* __restrict__ ctab,
                                                   const float* __restrict__ stab){
  int which = blockIdx.y;
  const short* src = qkv + (size_t)which * (NB * NH * NT * ND);
  short* dst = outp + (size_t)which * (NB * NH * NT * ND);
  const float* g = which ? gk : gq;
  const float* bb = which ? bk : bq;
  int wid = threadIdx.x >> 6, lane = threadIdx.x & 63;
  size_t row = (size_t)blockIdx.x * 4 + wid;  // over B*H*T
  int h = (int)((row >> 11) & 15);
  int t = (int)(row & 2047);
  const short* rp = src + row * ND;
  float v0 = bf2f(rp[lane]), v1 = bf2f(rp[lane + 64]);
  float mean = wredsum(v0 + v1) * (1.0f / 128.0f);
  float c0 = v0 - mean, c1 = v1 - mean;
  float ms = wredsum(c0 * c0 + c1 * c1) * (1.0f / 128.0f);
  float rstd = rsqrtf(ms + 1e-6f);
  float n0 = c0 * rstd * (1.0f + g[h * ND + lane]) + bb[h * ND + lane];
  float n1 = c1 * rstd * (1.0f + g[h * ND + lane + 64]) + bb[h * ND + lane + 64];
  float co = ctab[t * 64 + lane], si = stab[t * 64 + lane];
  short* wp = dst + row * ND;
  wp[lane]      = (short)f2bf(n0 * co - n1 * si);
  wp[lane + 64] = (short)f2bf(n0 * si + n1 * co);
}

// ---------------- flash attention, causal ----------------------------------
// K and V^T staged via global_load_lds with pre-swizzled global source
// (both-sides XOR swizzle); LDS double-buffered; 2-phase prefetch: one
// vmcnt(0)+barrier per tile, STAGE(jb+1) issued before compute(jb).
// LDS: K[2][64][256B] | V^T[2][128][128B] | Ps[4][2KB] = 72 KiB dynamic.
__global__ __launch_bounds__(256) void attn_k(const short* __restrict__ qn,
                                              const short* __restrict__ kn,
                                              const short* __restrict__ vt,
                                              short* __restrict__ ob){
  extern __shared__ char lds[];
  const int tid = threadIdx.x;
  const int wid = tid >> 6, lane = tid & 63;
  const int lrow = lane & 15, g8 = lane >> 4;
  const int bh = blockIdx.y;
  const int b = bh >> 4, h = bh & 15;
  const size_t base = (size_t)bh * NT * ND;
  char* Pw = lds + 65536 + wid * 2048;

  auto STAGE = [&](int cb, int jb){
    // K tile [64 rows][128 d] -> rows of 256B, granule slot g holds global
    // granule g^(r&7)
    #pragma unroll
    for (int i = 0; i < 4; ++i){
      int r0 = wid * 16 + i * 4;
      int r = r0 + (lane >> 4);
      int g = lane & 15;
      gload_lds16(kn + base + (size_t)(jb * 64 + r) * ND + ((g ^ (r & 7)) << 3),
                  lds + cb * 16384 + r0 * 256);
    }
    // V^T tile [128 rows d][64 t] -> rows of 128B, slot g holds g^(d&7)
    #pragma unroll
    for (int i = 0; i < 4; ++i){
      int d0 = wid * 32 + i * 8;
      int d = d0 + (lane >> 3);
      int g = lane & 7;
      gload_lds16(vt + base + (size_t)d * NT + jb * 64 + ((g ^ (d & 7)) << 3),
                  lds + 32768 + cb * 16384 + d0 * 128);
    }
  };

  for (int pass = 0; pass < 2; ++pass){
    const int qt = pass ? (31 - (int)blockIdx.x) : (int)blockIdx.x;
    const int t0 = qt * 64;
    const int tq = t0 + wid * 16 + lrow;
    bf16x8 qf[4];
    #pragma unroll
    for (int dc = 0; dc < 4; ++dc)
      qf[dc] = *(const bf16x8*)(qn + base + (size_t)tq * ND + dc * 32 + g8 * 8);
    f32x4 O[8] = {};
    float m = -3e38f, lsum = 0.0f;
    const int ntiles = qt + 1;

    __syncthreads();             // protect LDS buffers from previous pass
    STAGE(0, 0);

    for (int jb = 0; jb < ntiles; ++jb){
      const int cb = jb & 1;
      asm volatile("s_waitcnt vmcnt(0)" ::: "memory");
      __builtin_amdgcn_s_barrier();          // tile jb resident
      if (jb + 1 < ntiles) STAGE(cb ^ 1, jb + 1);   // prefetch overlaps compute
      const char* Kb = lds + cb * 16384;
      const char* Vb = lds + 32768 + cb * 16384;

      // ---- S^T = K * Q^T over D=128 ----
      f32x4 st[4] = {};
      #pragma unroll
      for (int dc = 0; dc < 4; ++dc)
        #pragma unroll
        for (int js = 0; js < 4; ++js){
          int jl = js * 16 + lrow;
          bf16x8 kf = *(const bf16x8*)(Kb + jl * 256 +
                        (((dc * 4 + g8) ^ (jl & 7)) << 4));
          st[js] = __builtin_amdgcn_mfma_f32_16x16x32_bf16(kf, qf[dc], st[js], 0, 0, 0);
        }
      // ---- scale + causal mask + row max ----
      float mx = -3e38f;
      #pragma unroll
      for (int js = 0; js < 4; ++js)
        #pragma unroll
        for (int r = 0; r < 4; ++r){
          float s = st[js][r] * (1.0f / 128.0f);
          int j = jb * 64 + js * 16 + g8 * 4 + r;
          if (j > tq) s = -3e38f;
          st[js][r] = s;
          mx = fmaxf(mx, s);
        }
      mx = fmaxf(mx, __shfl_xor(mx, 16));
      mx = fmaxf(mx, __shfl_xor(mx, 32));
      float mnew = fmaxf(m, mx);
      float fac = __expf(m - mnew);
      m = mnew;
      lsum *= fac;
      #pragma unroll
      for (int dcb = 0; dcb < 8; ++dcb) O[dcb] *= fac;
      // ---- P = exp(S - m), write to swizzled per-wave LDS ----
      float ps = 0.0f;
      #pragma unroll
      for (int js = 0; js < 4; ++js)
        #pragma unroll
        for (int r = 0; r < 4; ++r){
          float p = __expf(st[js][r] - mnew);
          ps += p;
          int jl = js * 16 + g8 * 4 + r;
          *(short*)(Pw + lrow * 128 + ((jl * 2) ^ ((lrow & 7) << 4))) = (short)f2bf(p);
        }
      ps += __shfl_xor(ps, 16);
      ps += __shfl_xor(ps, 32);
      lsum += ps;
      asm volatile("s_waitcnt lgkmcnt(0)" ::: "memory");
      // ---- O^T += V^T * P^T ----
      #pragma unroll
      for (int j32 = 0; j32 < 2; ++j32){
        bf16x8 pf = *(const bf16x8*)(Pw + lrow * 128 +
                      ((j32 * 64 + g8 * 16) ^ ((lrow & 7) << 4)));
        #pragma unroll
        for (int dcb = 0; dcb < 8; ++dcb){
          int d = dcb * 16 + lrow;
          bf16x8 vf = *(const bf16x8*)(Vb + d * 128 +
                        (((j32 * 4 + g8) ^ (d & 7)) << 4));
          O[dcb] = __builtin_amdgcn_mfma_f32_16x16x32_bf16(vf, pf, O[dcb], 0, 0, 0);
        }
      }
      __builtin_amdgcn_s_barrier();   // all reads of buffer cb done
    }
    // ---- write O row tq as bf16 into [bt][h*128+d] ----
    float inv = 1.0f / lsum;
    #pragma unroll
    for (int dcb = 0; dcb < 8; ++dcb){
      bf16x4 w4;
      #pragma unroll
      for (int r = 0; r < 4; ++r) w4[r] = (short)f2bf(O[dcb][r] * inv);
      *(bf16x4*)(ob + ((size_t)(b * NT + tq)) * (NH * ND) + h * ND + dcb * 16 + g8 * 4) = w4;
    }
  }
}

// ---------------------------------------------------------------------------
extern "C" void kernel_launch(void* const* d_in, const int* in_sizes, int n_in,
                              void* d_out, int out_size, void* d_ws, size_t ws_size,
                              hipStream_t stream){
  const float* x  = (const float*)d_in[0];
  const float* wq = (const float*)d_in[1];
  const float* wk = (const float*)d_in[2];
  const float* wv = (const float*)d_in[3];
  const float* wo = (const float*)d_in[4];
  const float* gq = (const float*)d_in[5];
  const float* bq = (const float*)d_in[6];
  const float* gk = (const float*)d_in[7];
  const float* bk = (const float*)d_in[8];

  char* ws = (char*)d_ws;
  short* xb   = (short*)(ws);                      // 16,777,216 B
  short* wT   = (short*)(ws + 16777216);           // 33,554,432 B (q,k,v,o ^T)
  short* qkvb = (short*)(ws + 50331648);           // 50,331,648 B (q|k|v^T bf16)
  short* qkn  = (short*)(ws + 100663296);          // 33,554,432 B (qn|kn)
  short* ob   = (short*)(ws + 134217728);          // 16,777,216 B
  float* ctab = (float*)(ws + 150994944);          // 524,288 B
  float* stab = (float*)(ws + 151519232);          // 524,288 B

  (void)hipFuncSetAttribute((const void*)gemm256_k,
                            hipFuncAttributeMaxDynamicSharedMemorySize, 131072);
  (void)hipFuncSetAttribute((const void*)attn_k,
                            hipFuncAttributeMaxDynamicSharedMemorySize, 73728);

  rope_table_k<<<dim3(2048), dim3(64), 0, stream>>>(ctab, stab);
  cast_x_k<<<dim3(8192), dim3(256), 0, stream>>>(x, xb);
  transpose_w_k<<<dim3(64, 64, 4), dim3(256), 0, stream>>>(wq, wk, wv, wo, wT);
  gemm256_k<<<dim3(384), dim3(512), 131072, stream>>>(xb, wT, qkvb);
  norm_rope_k<<<dim3(16384, 2), dim3(256), 0, stream>>>(qkvb, qkn, gq, bq, gk, bk, ctab, stab);
  attn_k<<<dim3(16, 32), dim3(256), 73728, stream>>>(qkn, qkn + 8388608,
                                                     qkvb + 2 * (size_t)8388608, ob);
  gemm_bt_k<<<dim3(32, 16), dim3(256), 0, stream>>>(ob, wT + 3 * (size_t)4194304,
                                                    (float*)d_out, 2048);
}

// Round 8
// 302.005 us; speedup vs baseline: 1.1561x; 1.0185x over previous
//
#include <hip/hip_runtime.h>

// ---------------------------------------------------------------------------
// Fused MHA: B=2, T=2048, M=2048, H=16, D=128, causal, qk-centered-RMS-norm,
// half-split rotary, QK_SCALE = 1/D.
// Pipeline: cast/transposes -> QKV GEMM (256^2 8-wave, R4 minimal-sync loop;
// V written tile-transposed [b][h][t/64][d][64]) -> norm+rope -> flash attn
// (gload_lds staging, 2-phase prefetch, dbuf LDS, setprio) -> out GEMM.
// ---------------------------------------------------------------------------

#define NB 2
#define NT 2048
#define NM 2048
#define NH 16
#define ND 128

typedef __attribute__((ext_vector_type(4))) float f32x4;
typedef __attribute__((ext_vector_type(8))) short bf16x8;
typedef __attribute__((ext_vector_type(4))) short bf16x4;

#define AS1 __attribute__((address_space(1)))
#define AS3 __attribute__((address_space(3)))

__device__ __forceinline__ unsigned short f2bf(float f){
  unsigned int u = __float_as_uint(f);
  u = (u + 0x7fffu + ((u >> 16) & 1u)) >> 16;   // RNE
  return (unsigned short)u;
}
__device__ __forceinline__ float bf2f(short s){
  return __uint_as_float(((unsigned int)(unsigned short)s) << 16);
}
__device__ __forceinline__ float wredsum(float v){
  #pragma unroll
  for (int m = 1; m < 64; m <<= 1) v += __shfl_xor(v, m);
  return v;
}
__device__ __forceinline__ void gload_lds16(const void* g, void* l){
  __builtin_amdgcn_global_load_lds((const AS1 void*)g, (AS3 void*)l, 16, 0, 0);
}

// ---------------- rope cos/sin table: [T][64] each --------------------------
__global__ __launch_bounds__(64) void rope_table_k(float* ctab, float* stab){
  int t = blockIdx.x, i = threadIdx.x;
  float freq = __expf(-(float)i * (9.210340371976184f / 64.0f)); // ln(10000)
  float ang = (float)t * freq;
  ctab[t * 64 + i] = cosf(ang);
  stab[t * 64 + i] = sinf(ang);
}

// ---------------- cast x fp32 -> bf16 --------------------------------------
__global__ __launch_bounds__(256) void cast_x_k(const float* __restrict__ x,
                                                short* __restrict__ xb){
  size_t gid = (size_t)blockIdx.x * 256 + threadIdx.x;
  float4 v = *(const float4*)(x + gid * 4);
  bf16x4 o;
  o[0] = (short)f2bf(v.x); o[1] = (short)f2bf(v.y);
  o[2] = (short)f2bf(v.z); o[3] = (short)f2bf(v.w);
  *(bf16x4*)(xb + gid * 4) = o;
}

// ------------- transpose weights fp32 [K][N] -> bf16 [N][K] ----------------
__global__ __launch_bounds__(256) void transpose_w_k(const float* __restrict__ wq,
                                                     const float* __restrict__ wk,
                                                     const float* __restrict__ wv,
                                                     const float* __restrict__ wo,
                                                     short* __restrict__ wT){
  __shared__ float tl[32][33];
  int z = blockIdx.z;
  const float* src = (z == 0) ? wq : (z == 1) ? wk : (z == 2) ? wv : wo;
  short* dst = wT + (size_t)z * 2048 * 2048;
  int n0 = blockIdx.x * 32, k0 = blockIdx.y * 32;
  int cx = threadIdx.x & 31, ry = threadIdx.x >> 5; // 0..7
  #pragma unroll
  for (int p = 0; p < 4; ++p)
    tl[ry + 8 * p][cx] = src[(size_t)(k0 + ry + 8 * p) * 2048 + n0 + cx];
  __syncthreads();
  #pragma unroll
  for (int p = 0; p < 4; ++p)
    dst[(size_t)(n0 + ry + 8 * p) * 2048 + k0 + cx] =
        (short)f2bf(tl[cx][ry + 8 * p]);
}

// ---------------------------------------------------------------------------
// QKV GEMM: C[4096 x 6144] = A[4096 x 2048] * B^T[6144 x 2048] (bf16)
// 256x256 tile, BK=64, 8 waves (2M x 4N), 512 threads, 128 KiB dynamic LDS.
// R4 minimal-sync K-loop. tsel is BLOCK-UNIFORM (by>>3). V written into
// KV-tile-tiled transpose [b][h][t/64][d][t&63] with bf16x4 stores.
// ---------------------------------------------------------------------------
#define NKT 32   // 2048 / 64
__global__ __launch_bounds__(512, 2) void gemm256_k(const short* __restrict__ A,
                                                    const short* __restrict__ Bt,
                                                    short* __restrict__ Cq){
  extern __shared__ char lds[];
  const int tid = threadIdx.x;
  const int wid = tid >> 6, lane = tid & 63;
  const int lrow = lane & 15, g8 = lane >> 4;
  const int wm = wid >> 2, wn = wid & 3;
  const int Kdim = 2048;

  // XCD-aware bijective swizzle over 384 blocks (384 % 8 == 0)
  int bid = blockIdx.x;
  int s = (bid & 7) * 48 + (bid >> 3);
  const int bx = s & 15;        // 16 m-tiles
  const int by = s >> 4;        // 24 n-tiles
  const int m0 = bx * 256, n0 = by * 256;

  const int r8 = lane >> 3;
  const int gcol = ((lane & 7) ^ r8) * 8;           // inverse-swizzled source
  const short* Ab = A  + (size_t)(m0 + wid * 8 + r8) * Kdim + gcol;
  const short* Bb = Bt + (size_t)(n0 + wid * 8 + r8) * Kdim + gcol;

  f32x4 acc[8][4] = {};

  auto STAGE = [&](int c, int kt){
    #pragma unroll
    for (int h = 0; h < 2; ++h)
      #pragma unroll
      for (int l = 0; l < 2; ++l){
        size_t roff = (size_t)(h * 128 + l * 64) * Kdim + kt * 64;
        char* la = lds + c * 32768 + h * 16384 + l * 8192 + wid * 1024;
        gload_lds16(Ab + roff, la);
        gload_lds16(Bb + roff, la + 65536);
      }
  };
  auto ldA = [&](int c, int mi, int kk) -> bf16x8 {
    int row = mi * 16 + lrow;
    int col = (kk * 64 + g8 * 16) ^ ((lrow & 7) << 4);
    return *(const bf16x8*)(lds + c * 32768 + wm * 16384 + row * 128 + col);
  };
  auto ldB = [&](int c, int ni, int kk) -> bf16x8 {
    int row = (wn & 1) * 64 + ni * 16 + lrow;
    int col = (kk * 64 + g8 * 16) ^ ((lrow & 7) << 4);
    return *(const bf16x8*)(lds + 65536 + c * 32768 + (wn >> 1) * 16384 + row * 128 + col);
  };

  STAGE(0, 0);   // prologue

  for (int kt = 0; kt < NKT; ++kt){
    const int c = kt & 1;
    asm volatile("s_waitcnt vmcnt(0)" ::: "memory");
    __builtin_amdgcn_s_barrier();
    if (kt + 1 < NKT) STAGE(c ^ 1, kt + 1);

    #pragma unroll
    for (int kk = 0; kk < 2; ++kk){
      bf16x8 bfr[4];
      #pragma unroll
      for (int ni = 0; ni < 4; ++ni) bfr[ni] = ldB(c, ni, kk);
      #pragma unroll
      for (int mh = 0; mh < 2; ++mh){
        bf16x8 afr[4];
        #pragma unroll
        for (int mi = 0; mi < 4; ++mi) afr[mi] = ldA(c, mh * 4 + mi, kk);
        #pragma unroll
        for (int mi = 0; mi < 4; ++mi)
          #pragma unroll
          for (int ni = 0; ni < 4; ++ni)
            acc[mh * 4 + mi][ni] = __builtin_amdgcn_mfma_f32_16x16x32_bf16(
                afr[mi], bfr[ni], acc[mh * 4 + mi][ni], 0, 0, 0);
      }
    }
  }

  // ---- epilogue: tsel block-uniform; q,k scalar scatter; v tiled bf16x4 ---
  const int tsel = by >> 3;           // 0=q, 1=k, 2=v
  short* dst = Cq + (size_t)tsel * (NB * NH * NT * ND);
  if (tsel < 2){
    #pragma unroll
    for (int mi = 0; mi < 8; ++mi){
      int rowb = m0 + wm * 128 + mi * 16 + g8 * 4;
      #pragma unroll
      for (int ni = 0; ni < 4; ++ni){
        int col = n0 + wn * 64 + ni * 16 + lrow;
        int hd = col & 2047;
        int hh = hd >> 7, d = hd & 127;
        f32x4 a = acc[mi][ni];
        #pragma unroll
        for (int r = 0; r < 4; ++r){
          int bt = rowb + r;
          int b = bt >> 11, t = bt & 2047;
          dst[(((size_t)(b * NH + hh)) * NT + t) * ND + d] = (short)f2bf(a[r]);
        }
      }
    }
  } else {
    #pragma unroll
    for (int mi = 0; mi < 8; ++mi){
      int rowb = m0 + wm * 128 + mi * 16 + g8 * 4;
      int b = rowb >> 11, t0 = rowb & 2047;
      int jb = t0 >> 6, toff = t0 & 63;     // 4 consecutive t stay in-tile
      #pragma unroll
      for (int ni = 0; ni < 4; ++ni){
        int col = n0 + wn * 64 + ni * 16 + lrow;
        int hd = col & 2047;
        int hh = hd >> 7, d = hd & 127;
        f32x4 a = acc[mi][ni];
        bf16x4 w4;
        #pragma unroll
        for (int r = 0; r < 4; ++r) w4[r] = (short)f2bf(a[r]);
        *(bf16x4*)&dst[(((size_t)(b * NH + hh) * 32 + jb) * ND + d) * 64 + toff] = w4;
      }
    }
  }
}

// ---------------- out-proj GEMM (128^2, double-buffered, 1-barrier) --------
// C[4096 x 2048] = A[4096 x K] * B^T[2048 x K], fp32 row-major out
__global__ __launch_bounds__(256) void gemm_bt_k(const short* __restrict__ A,
                                                 const short* __restrict__ Bt,
                                                 float* __restrict__ Cout,
                                                 int Kdim){
  __shared__ short As[2][128 * 32];
  __shared__ short Bs[2][128 * 32];
  const int tid = threadIdx.x;
  const int wid = tid >> 6, lane = tid & 63;
  const int lrow = lane & 15, g8 = lane >> 4;
  const int wm = wid >> 1, wn = wid & 1;
  const int m0 = blockIdx.x * 128, n0 = blockIdx.y * 128;
  f32x4 acc[4][4] = {};
  const int srow = lane >> 2;
  const int skcol = (lane & 3) * 8;

  auto STAGE = [&](int c, int kt){
    #pragma unroll
    for (int i = 0; i < 2; ++i){
      int inst = wid * 2 + i;
      int r = inst * 16 + srow;
      const short* sa = A  + (size_t)(m0 + r) * Kdim + kt + skcol;
      const short* sb = Bt + (size_t)(n0 + r) * Kdim + kt + skcol;
      gload_lds16(sa, (char*)As[c] + inst * 1024);
      gload_lds16(sb, (char*)Bs[c] + inst * 1024);
    }
  };

  STAGE(0, 0);
  const int nkt = Kdim >> 5;
  for (int it = 0; it < nkt; ++it){
    const int c = it & 1;
    asm volatile("s_waitcnt vmcnt(0)" ::: "memory");
    __builtin_amdgcn_s_barrier();
    if (it + 1 < nkt) STAGE(c ^ 1, (it + 1) << 5);

    bf16x8 af[4], bfv[4];
    #pragma unroll
    for (int mi = 0; mi < 4; ++mi)
      af[mi] = *(const bf16x8*)&As[c][(wm * 64 + mi * 16 + lrow) * 32 + g8 * 8];
    #pragma unroll
    for (int ni = 0; ni < 4; ++ni)
      bfv[ni] = *(const bf16x8*)&Bs[c][(wn * 64 + ni * 16 + lrow) * 32 + g8 * 8];
    #pragma unroll
    for (int mi = 0; mi < 4; ++mi)
      #pragma unroll
      for (int ni = 0; ni < 4; ++ni)
        acc[mi][ni] = __builtin_amdgcn_mfma_f32_16x16x32_bf16(
            af[mi], bfv[ni], acc[mi][ni], 0, 0, 0);
  }

  #pragma unroll
  for (int mi = 0; mi < 4; ++mi){
    int rowb = m0 + wm * 64 + mi * 16 + g8 * 4;
    #pragma unroll
    for (int ni = 0; ni < 4; ++ni){
      int col = n0 + wn * 64 + ni * 16 + lrow;
      f32x4 a = acc[mi][ni];
      #pragma unroll
      for (int r = 0; r < 4; ++r)
        Cout[(size_t)(rowb + r) * 2048 + col] = a[r];
    }
  }
}

// -------------- centered RMS norm + rotary (q and k) -----------------------
__global__ __launch_bounds__(256) void norm_rope_k(const short* __restrict__ qkv,
                                                   short* __restrict__ outp,
                                                   const float* __restrict__ gq,
                                                   const float* __restrict__ bq,
                                                   const float* __restrict__ gk,
                                                   const float* __restrict__ bk,
                                                   const float* __restrict__ ctab,
                                                   const float* __restrict__ stab){
  int which = blockIdx.y;
  const short* src = qkv + (size_t)which * (NB * NH * NT * ND);
  short* dst = outp + (size_t)which * (NB * NH * NT * ND);
  const float* g = which ? gk : gq;
  const float* bb = which ? bk : bq;
  int wid = threadIdx.x >> 6, lane = threadIdx.x & 63;
  size_t row = (size_t)blockIdx.x * 4 + wid;  // over B*H*T
  int h = (int)((row >> 11) & 15);
  int t = (int)(row & 2047);
  const short* rp = src + row * ND;
  float v0 = bf2f(rp[lane]), v1 = bf2f(rp[lane + 64]);
  float mean = wredsum(v0 + v1) * (1.0f / 128.0f);
  float c0 = v0 - mean, c1 = v1 - mean;
  float ms = wredsum(c0 * c0 + c1 * c1) * (1.0f / 128.0f);
  float rstd = rsqrtf(ms + 1e-6f);
  float n0 = c0 * rstd * (1.0f + g[h * ND + lane]) + bb[h * ND + lane];
  float n1 = c1 * rstd * (1.0f + g[h * ND + lane + 64]) + bb[h * ND + lane + 64];
  float co = ctab[t * 64 + lane], si = stab[t * 64 + lane];
  short* wp = dst + row * ND;
  wp[lane]      = (short)f2bf(n0 * co - n1 * si);
  wp[lane + 64] = (short)f2bf(n0 * si + n1 * co);
}

// ---------------- flash attention, causal ----------------------------------
// K and V^T staged via global_load_lds with pre-swizzled global source;
// V^T source is the tiled layout [b][h][jb][d][64]. LDS double-buffered;
// 2-phase prefetch; setprio around MFMA clusters.
// LDS: K[2][64][256B] | V^T[2][128][128B] | Ps[4][2KB] = 72 KiB dynamic.
__global__ __launch_bounds__(256) void attn_k(const short* __restrict__ qn,
                                              const short* __restrict__ kn,
                                              const short* __restrict__ vt,
                                              short* __restrict__ ob){
  extern __shared__ char lds[];
  const int tid = threadIdx.x;
  const int wid = tid >> 6, lane = tid & 63;
  const int lrow = lane & 15, g8 = lane >> 4;
  const int bh = blockIdx.y;
  const int b = bh >> 4, h = bh & 15;
  const size_t base = (size_t)bh * NT * ND;
  char* Pw = lds + 65536 + wid * 2048;

  auto STAGE = [&](int cb, int jb){
    // K tile [64 rows][128 d] -> rows of 256B, granule slot g holds g^(r&7)
    #pragma unroll
    for (int i = 0; i < 4; ++i){
      int r0 = wid * 16 + i * 4;
      int r = r0 + (lane >> 4);
      int g = lane & 15;
      gload_lds16(kn + base + (size_t)(jb * 64 + r) * ND + ((g ^ (r & 7)) << 3),
                  lds + cb * 16384 + r0 * 256);
    }
    // V^T tile (tiled source: jb*8192 + d*64) -> rows of 128B, slot g^(d&7)
    #pragma unroll
    for (int i = 0; i < 4; ++i){
      int d0 = wid * 32 + i * 8;
      int d = d0 + (lane >> 3);
      int g = lane & 7;
      gload_lds16(vt + base + (size_t)jb * 8192 + d * 64 + ((g ^ (d & 7)) << 3),
                  lds + 32768 + cb * 16384 + d0 * 128);
    }
  };

  for (int pass = 0; pass < 2; ++pass){
    const int qt = pass ? (31 - (int)blockIdx.x) : (int)blockIdx.x;
    const int t0 = qt * 64;
    const int tq = t0 + wid * 16 + lrow;
    bf16x8 qf[4];
    #pragma unroll
    for (int dc = 0; dc < 4; ++dc)
      qf[dc] = *(const bf16x8*)(qn + base + (size_t)tq * ND + dc * 32 + g8 * 8);
    f32x4 O[8] = {};
    float m = -3e38f, lsum = 0.0f;
    const int ntiles = qt + 1;

    __syncthreads();             // protect LDS buffers from previous pass
    STAGE(0, 0);

    for (int jb = 0; jb < ntiles; ++jb){
      const int cb = jb & 1;
      asm volatile("s_waitcnt vmcnt(0)" ::: "memory");
      __builtin_amdgcn_s_barrier();          // tile jb resident
      if (jb + 1 < ntiles) STAGE(cb ^ 1, jb + 1);   // prefetch overlaps compute
      const char* Kb = lds + cb * 16384;
      const char* Vb = lds + 32768 + cb * 16384;

      // ---- S^T = K * Q^T over D=128 ----
      f32x4 st[4] = {};
      __builtin_amdgcn_s_setprio(1);
      #pragma unroll
      for (int dc = 0; dc < 4; ++dc)
        #pragma unroll
        for (int js = 0; js < 4; ++js){
          int jl = js * 16 + lrow;
          bf16x8 kf = *(const bf16x8*)(Kb + jl * 256 +
                        (((dc * 4 + g8) ^ (jl & 7)) << 4));
          st[js] = __builtin_amdgcn_mfma_f32_16x16x32_bf16(kf, qf[dc], st[js], 0, 0, 0);
        }
      __builtin_amdgcn_s_setprio(0);
      // ---- scale + causal mask + row max ----
      float mx = -3e38f;
      #pragma unroll
      for (int js = 0; js < 4; ++js)
        #pragma unroll
        for (int r = 0; r < 4; ++r){
          float s = st[js][r] * (1.0f / 128.0f);
          int j = jb * 64 + js * 16 + g8 * 4 + r;
          if (j > tq) s = -3e38f;
          st[js][r] = s;
          mx = fmaxf(mx, s);
        }
      mx = fmaxf(mx, __shfl_xor(mx, 16));
      mx = fmaxf(mx, __shfl_xor(mx, 32));
      float mnew = fmaxf(m, mx);
      float fac = __expf(m - mnew);
      m = mnew;
      lsum *= fac;
      #pragma unroll
      for (int dcb = 0; dcb < 8; ++dcb) O[dcb] *= fac;
      // ---- P = exp(S - m), write to swizzled per-wave LDS ----
      float ps = 0.0f;
      #pragma unroll
      for (int js = 0; js < 4; ++js)
        #pragma unroll
        for (int r = 0; r < 4; ++r){
          float p = __expf(st[js][r] - mnew);
          ps += p;
          int jl = js * 16 + g8 * 4 + r;
          *(short*)(Pw + lrow * 128 + ((jl * 2) ^ ((lrow & 7) << 4))) = (short)f2bf(p);
        }
      ps += __shfl_xor(ps, 16);
      ps += __shfl_xor(ps, 32);
      lsum += ps;
      asm volatile("s_waitcnt lgkmcnt(0)" ::: "memory");
      // ---- O^T += V^T * P^T ----
      __builtin_amdgcn_s_setprio(1);
      #pragma unroll
      for (int j32 = 0; j32 < 2; ++j32){
        bf16x8 pf = *(const bf16x8*)(Pw + lrow * 128 +
                      ((j32 * 64 + g8 * 16) ^ ((lrow & 7) << 4)));
        #pragma unroll
        for (int dcb = 0; dcb < 8; ++dcb){
          int d = dcb * 16 + lrow;
          bf16x8 vf = *(const bf16x8*)(Vb + d * 128 +
                        (((j32 * 4 + g8) ^ (d & 7)) << 4));
          O[dcb] = __builtin_amdgcn_mfma_f32_16x16x32_bf16(vf, pf, O[dcb], 0, 0, 0);
        }
      }
      __builtin_amdgcn_s_setprio(0);
      __builtin_amdgcn_s_barrier();   // all reads of buffer cb done
    }
    // ---- write O row tq as bf16 into [bt][h*128+d] ----
    float inv = 1.0f / lsum;
    #pragma unroll
    for (int dcb = 0; dcb < 8; ++dcb){
      bf16x4 w4;
      #pragma unroll
      for (int r = 0; r < 4; ++r) w4[r] = (short)f2bf(O[dcb][r] * inv);
      *(bf16x4*)(ob + ((size_t)(b * NT + tq)) * (NH * ND) + h * ND + dcb * 16 + g8 * 4) = w4;
    }
  }
}

// ---------------------------------------------------------------------------
extern "C" void kernel_launch(void* const* d_in, const int* in_sizes, int n_in,
                              void* d_out, int out_size, void* d_ws, size_t ws_size,
                              hipStream_t stream){
  const float* x  = (const float*)d_in[0];
  const float* wq = (const float*)d_in[1];
  const float* wk = (const float*)d_in[2];
  const float* wv = (const float*)d_in[3];
  const float* wo = (const float*)d_in[4];
  const float* gq = (const float*)d_in[5];
  const float* bq = (const float*)d_in[6];
  const float* gk = (const float*)d_in[7];
  const float* bk = (const float*)d_in[8];

  char* ws = (char*)d_ws;
  short* xb   = (short*)(ws);                      // 16,777,216 B
  short* wT   = (short*)(ws + 16777216);           // 33,554,432 B (q,k,v,o ^T)
  short* qkvb = (short*)(ws + 50331648);           // 50,331,648 B (q|k|v^T bf16)
  short* qkn  = (short*)(ws + 100663296);          // 33,554,432 B (qn|kn)
  short* ob   = (short*)(ws + 134217728);          // 16,777,216 B
  float* ctab = (float*)(ws + 150994944);          // 524,288 B
  float* stab = (float*)(ws + 151519232);          // 524,288 B

  (void)hipFuncSetAttribute((const void*)gemm256_k,
                            hipFuncAttributeMaxDynamicSharedMemorySize, 131072);
  (void)hipFuncSetAttribute((const void*)attn_k,
                            hipFuncAttributeMaxDynamicSharedMemorySize, 73728);

  rope_table_k<<<dim3(2048), dim3(64), 0, stream>>>(ctab, stab);
  cast_x_k<<<dim3(8192), dim3(256), 0, stream>>>(x, xb);
  transpose_w_k<<<dim3(64, 64, 4), dim3(256), 0, stream>>>(wq, wk, wv, wo, wT);
  gemm256_k<<<dim3(384), dim3(512), 131072, stream>>>(xb, wT, qkvb);
  norm_rope_k<<<dim3(16384, 2), dim3(256), 0, stream>>>(qkvb, qkn, gq, bq, gk, bk, ctab, stab);
  attn_k<<<dim3(16, 32), dim3(256), 73728, stream>>>(qkn, qkn + 8388608,
                                                     qkvb + 2 * (size_t)8388608, ob);
  gemm_bt_k<<<dim3(32, 16), dim3(256), 0, stream>>>(ob, wT + 3 * (size_t)4194304,
                                                    (float*)d_out, 2048);
}